// Round 9
// baseline (321.624 us; speedup 1.0000x reference)
//
#include <hip/hip_runtime.h>
#include <hip/hip_bf16.h>
#include <stdint.h>

// out[m][n] = sum_k x[m][k] * centroids[idx[n][k]] + bias[n]
// M=8192, N=4096, K=4096. decode W->bf16, cvt x->bf16, then MFMA GEMM.
// Round 9: 128x128 tile / 256 threads / 64 KiB LDS -> TWO independent blocks
// per CU. Same verified schedule as r6 (1 barrier per K-tile, counted lgkm,
// vmcnt(4), 0-conflict swizzle); inter-block overlap hides the per-tile
// boundary stall (m114 mechanism).

typedef unsigned short u16;
typedef __attribute__((ext_vector_type(8))) short short8;   // bf16x8 (4 VGPR)
typedef __attribute__((ext_vector_type(8))) u16   u16x8;
typedef __attribute__((ext_vector_type(4))) float f32x4;
typedef __attribute__((ext_vector_type(4))) int   i32x4;

constexpr int Mdim = 8192;
constexpr int Ndim = 4096;
constexpr int Kdim = 4096;

__device__ __forceinline__ u16 f2bf(float f) {
  union { float f; uint32_t u; } v; v.f = f;
  uint32_t u = v.u;
  return (u16)((u + 0x7fffu + ((u >> 16) & 1u)) >> 16);
}

// ---------------- decode: weight_bf16[n*K + k] = bf16(cent[idx[n*K + k]]) ----
__global__ void decode_weight_kernel(const int* __restrict__ idx,
                                     const float* __restrict__ cent,
                                     u16* __restrict__ wb) {
  __shared__ u16 lut[256];
  const int t = threadIdx.x;
  if (t < 256) lut[t] = f2bf(cent[t]);
  __syncthreads();
  const size_t base = ((size_t)blockIdx.x * 256 + t) * 8;
  i32x4 i0 = *(const i32x4*)(idx + base);
  i32x4 i1 = *(const i32x4*)(idx + base + 4);
  u16x8 r;
  r[0] = lut[i0[0] & 255]; r[1] = lut[i0[1] & 255];
  r[2] = lut[i0[2] & 255]; r[3] = lut[i0[3] & 255];
  r[4] = lut[i1[0] & 255]; r[5] = lut[i1[1] & 255];
  r[6] = lut[i1[2] & 255]; r[7] = lut[i1[3] & 255];
  *(u16x8*)(wb + base) = r;
}

// ---------------- convert: x fp32 -> bf16 -----------------------------------
__global__ void cvt_x_kernel(const float* __restrict__ x, u16* __restrict__ xb) {
  const size_t base = ((size_t)blockIdx.x * 256 + threadIdx.x) * 8;
  f32x4 a = *(const f32x4*)(x + base);
  f32x4 b = *(const f32x4*)(x + base + 4);
  u16x8 r;
  r[0] = f2bf(a[0]); r[1] = f2bf(a[1]); r[2] = f2bf(a[2]); r[3] = f2bf(a[3]);
  r[4] = f2bf(b[0]); r[5] = f2bf(b[1]); r[6] = f2bf(b[2]); r[7] = f2bf(b[3]);
  *(u16x8*)(xb + base) = r;
}

// ---------------- async 16B global -> LDS -----------------------------------
__device__ __forceinline__ void async16(const u16* g, u16* l) {
  __builtin_amdgcn_global_load_lds(
      (const __attribute__((address_space(1))) void*)g,
      (__attribute__((address_space(3))) void*)l,
      16, 0, 0);
}

#define BAR()   __builtin_amdgcn_s_barrier()
#define SCB()   __builtin_amdgcn_sched_barrier(0)
#define LGKM0() do { asm volatile("s_waitcnt lgkmcnt(0)" ::: "memory"); SCB(); } while (0)
#define LGKM2() do { asm volatile("s_waitcnt lgkmcnt(2)" ::: "memory"); SCB(); } while (0)
#define VMC4()  asm volatile("s_waitcnt vmcnt(4)" ::: "memory")
#define VMC0()  asm volatile("s_waitcnt vmcnt(0)" ::: "memory")

// ---------------- 128x128 bf16 GEMM, 1 barrier per K-tile, 2 blocks/CU ------
// 256 threads = 4 waves (2 M x 2 N), wave tile 64x64 (4x4 16x16 frags).
// BK=64, dbuf LDS 64 KiB total. LDS tile (128 rows x 64 cols bf16, 16 KiB):
// 16x32-elem subtiles; quad slot = (col>>3) ^ ((row>>1)&3) — 0 bank conflicts
// (verified r3). Per-wave ds_reads pipelined one phase ahead (counted lgkm);
// one vmcnt(4)+s_barrier per K-tile.
__global__ __launch_bounds__(256, 2)
void gemm_bf16_kernel(const u16* __restrict__ A,   // [Mdim][Kdim] bf16
                      const u16* __restrict__ B,   // [Ndim][Kdim] bf16
                      const float* __restrict__ bias,
                      float* __restrict__ C) {
  __shared__ u16 AsF[16384];   // [buf][8192 elems] = 32 KiB
  __shared__ u16 BsF[16384];

  const int t    = threadIdx.x;
  const int lane = t & 63;
  const int w    = t >> 6;      // wave 0..3
  const int wm   = w >> 1;      // 0..1 -> A rows wm*64..+63
  const int wn   = w & 1;       // 0..1 -> B rows wn*64..+63
  const int fr   = lane & 15;
  const int fq   = lane >> 4;
  const int cswz = (fr & 6) << 2;   // ((fr>>1)&3)*8

  // L2-aware XCD map: 2048 blocks; XCD x owns mt in [x*8, x*8+8); nt cycles
  // by round. 4 co-XCD blocks share each A-panel, 8 share each B-panel.
  const int bid   = blockIdx.x;
  const int xcd   = bid & 7;
  const int wi    = (bid >> 3) & 31;
  const int round = bid >> 8;                 // 0..7
  const int mt = xcd * 8 + (wi >> 2);         // 0..63
  const int nt = round * 4 + (wi & 3);        // 0..31
  const int m0 = mt * 128;
  const int n0 = nt * 128;

  // staging: 128x64 tile = 16 KiB = 1024 chunks of 16 B; thread t takes
  // chunks c = t + l*256, l=0..3. c bits: [1:0]=quad [5:2]=r16 [6]=colhalf
  // [9:7]=rowgroup. Source col pre-swizzled; LDS dest linear (elem c*8).
  int srcOff[4];
#pragma unroll
  for (int l = 0; l < 4; ++l) {
    const int c    = t + l * 256;
    const int r16s = (c & 63) >> 2;
    const int srow = ((c >> 7) << 4) + r16s;
    const int scol = ((c >> 6) & 1) * 32 + (((c & 3) * 8) ^ ((r16s & 6) << 2));
    srcOff[l] = srow * Kdim + scol;
  }
  const int dsto = t * 8;
  const u16* pA = A + (size_t)m0 * Kdim;
  const u16* pB = B + (size_t)n0 * Kdim;

  // fragment bases: elem(row r, col k) = (r>>4)*1024 + (k>>5)*512 +
  //   (r&15)*32 + (((k>>3)&3)^((r>>1)&3))*8 + (k&7)
  const int aBase = fr * 32 + ((fq * 8) ^ cswz);   // + (wm*4+mi)*1024 + kk*512
  const int bBase = fr * 32 + ((fq * 8) ^ cswz);   // + (wn*4+ni)*1024 + kk*512

  f32x4 acc[4][4] = {};
  short8 bf[2][4];      // [kk][ni], refreshed at tile boundary
  short8 afE[2];        // A frags even phases (q0,q2), [kk]
  short8 afO[2];        // A frags odd phases (q1,q3)

  auto stA = [&](int tk, int l) {
    async16(pA + srcOff[l] + tk * 64, &AsF[((tk & 1) << 13) + dsto + l * 2048]);
  };
  auto stB = [&](int tk, int l) {
    async16(pB + srcOff[l] + tk * 64, &BsF[((tk & 1) << 13) + dsto + l * 2048]);
  };
  auto rdB_kk = [&](int buf, int kk) {
#pragma unroll
    for (int ni = 0; ni < 4; ++ni)
      bf[kk][ni] = *(const short8*)&BsF[(buf << 13) + bBase + (wn * 4 + ni) * 1024 + kk * 512];
  };
  auto rdA_E = [&](int buf, int mi) {
#pragma unroll
    for (int kk = 0; kk < 2; ++kk)
      afE[kk] = *(const short8*)&AsF[(buf << 13) + aBase + (wm * 4 + mi) * 1024 + kk * 512];
  };
  auto rdA_O = [&](int buf, int mi) {
#pragma unroll
    for (int kk = 0; kk < 2; ++kk)
      afO[kk] = *(const short8*)&AsF[(buf << 13) + aBase + (wm * 4 + mi) * 1024 + kk * 512];
  };
  auto mfmaE = [&](int q) {   // 8 MFMA into acc[q]
    __builtin_amdgcn_s_setprio(1);
#pragma unroll
    for (int kk = 0; kk < 2; ++kk)
#pragma unroll
      for (int ni = 0; ni < 4; ++ni)
        acc[q][ni] = __builtin_amdgcn_mfma_f32_16x16x32_bf16(
            afE[kk], bf[kk][ni], acc[q][ni], 0, 0, 0);
    __builtin_amdgcn_s_setprio(0);
  };
  auto mfmaO = [&](int q) {
    __builtin_amdgcn_s_setprio(1);
#pragma unroll
    for (int kk = 0; kk < 2; ++kk)
#pragma unroll
      for (int ni = 0; ni < 4; ++ni)
        acc[q][ni] = __builtin_amdgcn_mfma_f32_16x16x32_bf16(
            afO[kk], bf[kk][ni], acc[q][ni], 0, 0, 0);
    __builtin_amdgcn_s_setprio(0);
  };
  auto mfmaO_kk = [&](int q, int kk) {   // one kk-half (4 MFMA)
    __builtin_amdgcn_s_setprio(1);
#pragma unroll
    for (int ni = 0; ni < 4; ++ni)
      acc[q][ni] = __builtin_amdgcn_mfma_f32_16x16x32_bf16(
          afO[kk], bf[kk][ni], acc[q][ni], 0, 0, 0);
    __builtin_amdgcn_s_setprio(0);
  };

  // Tile T (BUF=T&1). Entry invariant: 10 boundary ds_reads (bf 8 + afE(q0) 2)
  // in flight; vmem outstanding = 4 = B(T+1).
  // MODE: 0 normal (vmcnt(4)); 1 tile 62 (no B stage, vmcnt(0)); 2 last.
#define KT(TK, BUF, DOA, DOB, MODE)                                     \
  {                                                                     \
    /* p0 */                                                            \
    rdA_O((BUF), 1);                                                    \
    if (DOA) { stA((TK) + 1, 0); stA((TK) + 1, 1); }                    \
    LGKM2();                 /* boundary 10 done; q1 in flight */       \
    mfmaE(0);                                                           \
    /* p1 */                                                            \
    rdA_E((BUF), 2);                                                    \
    if (DOA) { stA((TK) + 1, 2); stA((TK) + 1, 3); }                    \
    if (DOB) { stB((TK) + 2, 0); stB((TK) + 2, 1); }                    \
    LGKM2();                 /* q1 done */                              \
    mfmaO(1);                                                           \
    /* p2 */                                                            \
    rdA_O((BUF), 3);                                                    \
    if (DOB) { stB((TK) + 2, 2); stB((TK) + 2, 3); }                    \
    LGKM2();                 /* q2 done */                              \
    mfmaE(2);                                                           \
    /* p3: the one cross-wave sync point per K-tile */                  \
    if ((MODE) == 0) { VMC4(); } else if ((MODE) == 1) { VMC0(); }      \
    BAR();                   /* all waves: A(T+1)/B(T+1) landed */      \
    LGKM0();                 /* q3 reads done */                        \
    mfmaO_kk(3, 0);                                                     \
    if ((MODE) < 2) rdB_kk((BUF) ^ 1, 0);                               \
    mfmaO_kk(3, 1);                                                     \
    if ((MODE) < 2) { rdB_kk((BUF) ^ 1, 1); rdA_E((BUF) ^ 1, 0); }      \
  }

  // Prologue: stage A(0),B(0),B(1) (12 loads); vmcnt(4) -> A(0),B(0) landed,
  // B(1) in flight; barrier; boundary reads for tile 0.
#pragma unroll
  for (int l = 0; l < 4; ++l) stA(0, l);
#pragma unroll
  for (int l = 0; l < 4; ++l) stB(0, l);
#pragma unroll
  for (int l = 0; l < 4; ++l) stB(1, l);
  VMC4();
  BAR();
  rdB_kk(0, 0); rdB_kk(0, 1); rdA_E(0, 0);

  for (int t2 = 0; t2 < 31; ++t2) {       // K-tiles 0..61
    KT(2 * t2,     0, 1, 1, 0);
    KT(2 * t2 + 1, 1, 1, 1, 0);
  }
  KT(62, 0, 1, 0, 1);                     // stage A(63); drain vmcnt to 0
  KT(63, 1, 0, 0, 2);                     // last: no staging, no boundary

  // Epilogue: C/D map col=lane&15, row=(lane>>4)*4+j  [m89]
  float bv[4];
#pragma unroll
  for (int ni = 0; ni < 4; ++ni)
    bv[ni] = bias[n0 + wn * 64 + ni * 16 + fr];

#pragma unroll
  for (int mi = 0; mi < 4; ++mi) {
#pragma unroll
    for (int j = 0; j < 4; ++j) {
      const int row = m0 + wm * 64 + mi * 16 + fq * 4 + j;
      float* cp = C + (size_t)row * Ndim + n0 + wn * 64 + fr;
#pragma unroll
      for (int ni = 0; ni < 4; ++ni)
        cp[ni * 16] = acc[mi][ni][j] + bv[ni];
    }
  }
#undef KT
}

extern "C" void kernel_launch(void* const* d_in, const int* in_sizes, int n_in,
                              void* d_out, int out_size, void* d_ws, size_t ws_size,
                              hipStream_t stream) {
  const float* x    = (const float*)d_in[0];   // [8192][4096] fp32
  const float* cent = (const float*)d_in[1];   // [256] fp32
  const float* bias = (const float*)d_in[2];   // [4096] fp32
  const int*   idx  = (const int*)d_in[3];     // [4096][4096] int
  float* out = (float*)d_out;                  // [8192][4096] fp32

  u16* wb = (u16*)d_ws;
  u16* xb = (u16*)((char*)d_ws + (size_t)Ndim * Kdim * sizeof(u16));

  decode_weight_kernel<<<(Ndim * Kdim) / (256 * 8), 256, 0, stream>>>(idx, cent, wb);
  cvt_x_kernel<<<((size_t)Mdim * Kdim) / (256 * 8), 256, 0, stream>>>(x, xb);

  gemm_bf16_kernel<<<dim3(2048), 256, 0, stream>>>(xb, wb, bias, out);
}